// Round 5
// baseline (108.383 us; speedup 1.0000x reference)
//
#include <hip/hip_runtime.h>
#include <math.h>

// Problem constants (fixed by the reference):
#define B  64
#define D  256
#define E  512
#define ND 1024

#define POISON 0xAAAAAAAAu

// ws offsets (4-byte units). Harness poisons ws with 0xAA before every launch.
#define TICKET_OFF 0      // [1]   uint ticket (starts at POISON)
#define C1_OFF     64     // [1]   float: sum_e log1p(-p_e)
#define T1P_OFF    128    // [16]  t1 partials (diagonal tiles)
#define T2P_OFF    256    // [256] t2 partials (one per tile)

// One block per 64x64 directed tile (I,J) of kwz  <->  32x32 undirected (e,f) tile.
// Everything the block needs (signs, weights, Q tile) is computed locally from
// det/pebz/para via bit-parallel parity — no inter-block dependency until the
// single ticketed finisher.
__global__ __launch_bounds__(256) void fused_k(const int* __restrict__ det,
                                               const int* __restrict__ pebz,
                                               const float* __restrict__ para,
                                               const float* __restrict__ kwz,
                                               float* __restrict__ ws,
                                               float* __restrict__ out) {
    unsigned* wsu = (unsigned*)ws;
    const int blk = blockIdx.x;   // 0..255
    const int tid = threadIdx.x;  // 0..255
    const int wv  = tid >> 6;     // wave 0..3
    const int ln  = tid & 63;     // lane 0..63
    const int I = blk >> 4, J = blk & 15;
    const int e0 = I * 32, f0 = J * 32;

    __shared__ unsigned long long detp[4][64];   // [seg][b] det bits d=seg*64..+63
    __shared__ unsigned long long masks[256];    // [d] pebz bits over the 64 cols
    __shared__ unsigned long long segP[4][64];   // per-seg parity partials
    __shared__ unsigned long long Pb[64];        // [b] parity bits over 64 cols
    __shared__ float wcols[64];                  // w = p/(1-p) for the 64 cols
    __shared__ float We[64 * 32];                // W[b][e-tile]
    __shared__ float Wf[64 * 32];                // W[b][f-tile]
    __shared__ float ldsQ[32 * 33];              // Q tile (pad 33)
    __shared__ float ldsT[64 * 65];              // kwz^T tile (pad 65: 2-way, free)
    __shared__ float red[256];
    __shared__ int   amLast;

    // ---- Stage A: pack det rows into bit masks (ballot, coalesced loads) ----
    #pragma unroll 4
    for (int it = 0; it < 64; ++it) {
        int idx = wv * 64 + it;              // 256 (b,seg) pairs over 4 waves
        int b = idx >> 2, seg = idx & 3;
        int v = det[b * D + seg * 64 + ln];
        unsigned long long m = __ballot(v != 0);
        if (ln == 0) detp[seg][b] = m;
    }

    // ---- Stage B: pack pebz rows restricted to this block's 64 columns ----
    const int colL = (ln < 32) ? (e0 + ln) : (f0 + ln - 32);
    #pragma unroll 4
    for (int it = 0; it < 64; ++it) {
        int d = wv * 64 + it;
        int v = pebz[(size_t)d * E + colL];  // two coalesced 128B runs
        unsigned long long m = __ballot(v != 0);
        if (ln == 0) masks[d] = m;
    }
    __syncthreads();

    // ---- Stage C: parity P[b] = XOR_{d: det[b][d]=1} masks[d] ----
    {
        const int b = ln, seg = wv;
        unsigned long long db = detp[seg][b];
        unsigned long long m = 0ULL;
        const unsigned long long* mp = &masks[seg * 64];
        #pragma unroll 8
        for (int dd = 0; dd < 64; ++dd)      // mp[dd] is wave-broadcast (free)
            m ^= mp[dd] & (0ULL - ((db >> dd) & 1ULL));
        segP[seg][b] = m;
    }
    __syncthreads();
    if (tid < 64)
        Pb[tid] = segP[0][tid] ^ segP[1][tid] ^ segP[2][tid] ^ segP[3][tid];
    if (tid >= 64 && tid < 128) {            // weights for the 64 cols
        int c = tid - 64;
        int col = (c < 32) ? (e0 + c) : (f0 + c - 32);
        float x = para[col];
        float p = 1.0f / (1.0f + expf(-x)) + 1e-20f;
        wcols[c] = p / (1.0f - p);
    }
    __syncthreads();

    // ---- Stage E: build signed-weight tiles We/Wf ----
    #pragma unroll
    for (int k = 0; k < 16; ++k) {
        int pair = tid + 256 * k;
        int b = pair >> 6;                   // wave-uniform -> Pb broadcast
        int c = pair & 63;
        float val = wcols[c];
        if ((Pb[b] >> c) & 1ULL) val = -val;
        if (c < 32) We[b * 32 + c] = val;
        else        Wf[b * 32 + (c - 32)] = val;
    }
    __syncthreads();

    // ---- Stage F: Q tile Q[e][f] = sum_b We[b][e]*Wf[b][f] ----
    {
        const int tf = tid & 31, teo = tid >> 5;   // teo 0..7
        float qa[4] = {0.f, 0.f, 0.f, 0.f};
        for (int b2 = 0; b2 < B; ++b2) {
            float wf = Wf[b2 * 32 + tf];
            #pragma unroll
            for (int r4 = 0; r4 < 4; ++r4)
                qa[r4] += We[b2 * 32 + teo + 8 * r4] * wf;
        }
        #pragma unroll
        for (int r4 = 0; r4 < 4; ++r4)
            ldsQ[(teo + 8 * r4) * 33 + tf] = qa[r4];
    }
    // transpose-source kwz tile for K_ji (overlaps with Q compute)
    {
        const int c = tid & 63, r0 = tid >> 6;
        #pragma unroll
        for (int p2 = 0; p2 < 16; ++p2) {
            int rr = r0 + 4 * p2;
            ldsT[rr * 65 + c] = kwz[(size_t)(J * 64 + rr) * ND + (I * 64 + c)];
        }
    }
    __syncthreads();

    // ---- Stage G: t2 partial = sum_tile K_ij * K_ji * Q[i/2][j/2] ----
    {
        const int c = tid & 63, r0 = tid >> 6;
        float acc2 = 0.0f;
        #pragma unroll
        for (int p2 = 0; p2 < 16; ++p2) {
            int r = r0 + 4 * p2;
            float kij = kwz[(size_t)(I * 64 + r) * ND + (J * 64 + c)]; // coalesced
            float kji = ldsT[c * 65 + r];                              // bank-clean
            float qv  = ldsQ[(r >> 1) * 33 + (c >> 1)];                // 2-way
            acc2 += kij * kji * qv;
        }
        red[tid] = acc2;
    }
    __syncthreads();
    for (int s = 128; s > 0; s >>= 1) {
        if (tid < s) red[tid] += red[tid + s];
        __syncthreads();
    }
    if (tid == 0)
        __hip_atomic_store(&ws[T2P_OFF + blk], red[0],
                           __ATOMIC_RELAXED, __HIP_MEMORY_SCOPE_AGENT);

    // ---- Stage H: diagonal blocks add t1 partial for their e-range ----
    if (I == J) {
        float v = 0.0f;
        if (tid < 32) {
            float sw = 0.0f;
            for (int b2 = 0; b2 < B; ++b2) sw += We[b2 * 32 + tid];
            int e = e0 + tid;
            float dd = kwz[(size_t)(2 * e) * ND + (2 * e)]
                     + kwz[(size_t)(2 * e + 1) * ND + (2 * e + 1)];
            v = sw * dd;
        }
        __syncthreads();
        red[tid] = v;
        __syncthreads();
        for (int s = 128; s > 0; s >>= 1) {
            if (tid < s) red[tid] += red[tid + s];
            __syncthreads();
        }
        if (tid == 0)
            __hip_atomic_store(&ws[T1P_OFF + I], red[0],
                               __ATOMIC_RELAXED, __HIP_MEMORY_SCOPE_AGENT);
    }

    // ---- Stage I: block 0 computes c1 = sum_e log1p(-p_e) ----
    if (blk == 0) {
        float x0 = para[tid], x1 = para[tid + 256];
        float p0 = 1.0f / (1.0f + expf(-x0)) + 1e-20f;
        float p1 = 1.0f / (1.0f + expf(-x1)) + 1e-20f;
        __syncthreads();
        red[tid] = log1pf(-p0) + log1pf(-p1);
        __syncthreads();
        for (int s = 128; s > 0; s >>= 1) {
            if (tid < s) red[tid] += red[tid + s];
            __syncthreads();
        }
        if (tid == 0)
            __hip_atomic_store(&ws[C1_OFF], red[0],
                               __ATOMIC_RELAXED, __HIP_MEMORY_SCOPE_AGENT);
    }

    // ---- Ticket: last block to arrive assembles the loss (no spinning) ----
    __syncthreads();   // drains each wave's outstanding stores (vmcnt(0))
    if (tid == 0) {
        unsigned old = __hip_atomic_fetch_add(&wsu[TICKET_OFF], 1u,
                                              __ATOMIC_ACQ_REL,
                                              __HIP_MEMORY_SCOPE_AGENT);
        amLast = (old == POISON + 255u || old == 255u) ? 1 : 0;
    }
    __syncthreads();
    if (amLast) {
        float v = __hip_atomic_load(&ws[T2P_OFF + tid], __ATOMIC_RELAXED,
                                    __HIP_MEMORY_SCOPE_AGENT) * (0.25f / (float)B);
        if (tid < 16)
            v += __hip_atomic_load(&ws[T1P_OFF + tid], __ATOMIC_RELAXED,
                                   __HIP_MEMORY_SCOPE_AGENT) * (0.5f / (float)B);
        if (tid == 0)
            v -= __hip_atomic_load(&ws[C1_OFF], __ATOMIC_RELAXED,
                                   __HIP_MEMORY_SCOPE_AGENT);
        red[tid] = v;
        __syncthreads();
        for (int s = 128; s > 0; s >>= 1) {
            if (tid < s) red[tid] += red[tid + s];
            __syncthreads();
        }
        if (tid == 0) out[0] = red[0];
    }
}

extern "C" void kernel_launch(void* const* d_in, const int* in_sizes, int n_in,
                              void* d_out, int out_size, void* d_ws, size_t ws_size,
                              hipStream_t stream) {
    const int*   det  = (const int*)d_in[0];    // [B, D]
    const int*   pebz = (const int*)d_in[1];    // [D, E]
    const float* para = (const float*)d_in[2];  // [E]
    const float* kwz  = (const float*)d_in[3];  // [ND, ND]
    // d_in[4] = edges_dict_z (arange(ND)//2, deterministic -> hardcoded)
    float* ws  = (float*)d_ws;
    float* out = (float*)d_out;

    hipLaunchKernelGGL(fused_k, dim3(256), dim3(256), 0, stream,
                       det, pebz, para, kwz, ws, out);
}

// Round 6
// 95.561 us; speedup vs baseline: 1.1342x; 1.1342x over previous
//
#include <hip/hip_runtime.h>
#include <math.h>

// Problem constants (fixed by the reference):
#define B  64
#define D  256
#define E  512
#define ND 1024

#define POISON 0xAAAAAAAAu

// ws offsets (4-byte units). Harness poisons ws with 0xAA before every launch.
#define TICKET_OFF 0      // [1]   uint ticket (starts at POISON)
#define C1_OFF     64     // [1]   float: sum_e log1p(-p_e)
#define T1P_OFF    128    // [16]  t1 partials (diagonal tiles)
#define T2P_OFF    256    // [256] t2 partials (one per tile)

// One block per 64x64 directed tile (I,J) of kwz <-> 32x32 undirected (e,f) tile.
// All global loads (kwz tiles, det, pebz, para) are issued up-front and
// independently; everything downstream is LDS/VALU. No inter-block sync except
// the final atomic ticket.
__global__ __launch_bounds__(256) void fused_k(const int* __restrict__ det,
                                               const int* __restrict__ pebz,
                                               const float* __restrict__ para,
                                               const float* __restrict__ kwz,
                                               float* __restrict__ ws,
                                               float* __restrict__ out) {
    unsigned* wsu = (unsigned*)ws;
    const int blk = blockIdx.x;   // 0..255
    const int tid = threadIdx.x;  // 0..255
    const int wv  = tid >> 6;     // wave 0..3
    const int ln  = tid & 63;     // lane 0..63
    const int I = blk >> 4, J = blk & 15;
    const int e0 = I * 32, f0 = J * 32;
    const int c  = ln;            // col within 64x64 tile
    const int r0 = wv;            // rows r0 + 4p

    __shared__ unsigned long long detw[64 * 5];  // [b*5+k], pad 5 (bank spread)
    __shared__ unsigned long long mask[256];     // [d] pebz bits over 64 cols
    __shared__ unsigned long long segP[256];     // per-seg parity partials
    __shared__ unsigned long long Pb[64];        // [b] parity bits over 64 cols
    __shared__ float wcols[64];                  // w = p/(1-p) for the 64 cols
    __shared__ float We[64 * 32];                // W[b][e-tile]
    __shared__ float Wf[64 * 32];                // W[b][f-tile]
    __shared__ float ldsQ[32 * 33];              // Q tile (pad 33)
    __shared__ float ldsT[64 * 65];              // kwz^T tile (pad 65: 2-way, free)
    __shared__ float red4[8];
    __shared__ int   amLast;

    // ---- Issue ALL kwz tile loads first (32 independent b32, coalesced) ----
    float kijv[16];
    #pragma unroll
    for (int p = 0; p < 16; ++p)
        kijv[p] = kwz[(size_t)(I * 64 + r0 + 4 * p) * ND + (J * 64 + c)];
    {
        float kjiv[16];
        #pragma unroll
        for (int p = 0; p < 16; ++p)
            kjiv[p] = kwz[(size_t)(J * 64 + r0 + 4 * p) * ND + (I * 64 + c)];
        #pragma unroll
        for (int p = 0; p < 16; ++p)
            ldsT[(r0 + 4 * p) * 65 + c] = kjiv[p];
    }

    // ---- Weights for this block's 64 cols (wave 1 only; overlaps loads) ----
    if (wv == 1) {
        int col = (ln < 32) ? (e0 + ln) : (f0 + ln - 32);
        float x = para[col];
        float prob = 1.0f / (1.0f + expf(-x)) + 1e-20f;
        wcols[ln] = prob / (1.0f - prob);
    }

    // ---- det packing: one int4 load per row b (wave wv owns b = wv*16+it) ----
    // Component-bit layout: detw[b][k] bit l == det[b][4l+k].
    const int4* det4 = (const int4*)det;
    #pragma unroll 4
    for (int it = 0; it < 16; ++it) {
        int b = wv * 16 + it;
        int4 v = det4[b * 64 + ln];
        unsigned long long m0 = __ballot(v.x != 0);
        unsigned long long m1 = __ballot(v.y != 0);
        unsigned long long m2 = __ballot(v.z != 0);
        unsigned long long m3 = __ballot(v.w != 0);
        if (ln == 0) {
            detw[b * 5 + 0] = m0; detw[b * 5 + 1] = m1;
            detw[b * 5 + 2] = m2; detw[b * 5 + 3] = m3;
        }
    }

    // ---- pebz masks over this block's 64 cols (independent b32 loads) ----
    const int colL = (ln < 32) ? (e0 + ln) : (f0 + ln - 32);
    #pragma unroll 8
    for (int it = 0; it < 64; ++it) {
        int d = wv * 64 + it;
        int v = pebz[(size_t)d * E + colL];
        unsigned long long m = __ballot(v != 0);
        if (ln == 0) mask[d] = m;
    }
    __syncthreads();

    // ---- Parity: P[b] = XOR_{d: det[b][d]=1} mask[d] (LDS-only) ----
    {
        const int b = ln, seg = wv;   // thread (seg, b)
        unsigned long long db0 = detw[b * 5 + 0], db1 = detw[b * 5 + 1],
                           db2 = detw[b * 5 + 2], db3 = detw[b * 5 + 3];
        const unsigned long long* mp = &mask[seg * 64];
        unsigned long long m = 0ULL;
        #pragma unroll
        for (int g = 0; g < 16; ++g) {        // d = seg*64 + 4g + k
            unsigned sh = (unsigned)(seg * 16 + g);
            m ^= mp[4 * g + 0] & (0ULL - ((db0 >> sh) & 1ULL));
            m ^= mp[4 * g + 1] & (0ULL - ((db1 >> sh) & 1ULL));
            m ^= mp[4 * g + 2] & (0ULL - ((db2 >> sh) & 1ULL));
            m ^= mp[4 * g + 3] & (0ULL - ((db3 >> sh) & 1ULL));
        }
        segP[seg * 64 + b] = m;
    }
    __syncthreads();
    if (tid < 64)
        Pb[tid] = segP[tid] ^ segP[64 + tid] ^ segP[128 + tid] ^ segP[192 + tid];
    __syncthreads();

    // ---- Signed weight tiles We/Wf ----
    #pragma unroll
    for (int k = 0; k < 16; ++k) {
        int pair = tid + 256 * k;
        int b  = pair >> 6;                  // wave-uniform -> Pb broadcast
        int cc = pair & 63;
        float val = wcols[cc];
        if ((Pb[b] >> cc) & 1ULL) val = -val;
        if (cc < 32) We[b * 32 + cc] = val;
        else         Wf[b * 32 + (cc - 32)] = val;
    }
    __syncthreads();

    // ---- Q tile: Q[e][f] = sum_b We[b][e]*Wf[b][f] ----
    {
        const int tf = tid & 31, teo = tid >> 5;
        float qa[4] = {0.f, 0.f, 0.f, 0.f};
        for (int b2 = 0; b2 < B; ++b2) {
            float wf = Wf[b2 * 32 + tf];
            #pragma unroll
            for (int r4 = 0; r4 < 4; ++r4)
                qa[r4] += We[b2 * 32 + teo + 8 * r4] * wf;
        }
        #pragma unroll
        for (int r4 = 0; r4 < 4; ++r4)
            ldsQ[(teo + 8 * r4) * 33 + tf] = qa[r4];
    }
    __syncthreads();

    // ---- Contraction: t2 partial = sum_tile K_ij (regs) * K_ji (LDS) * Q ----
    {
        float acc2 = 0.0f;
        #pragma unroll
        for (int p = 0; p < 16; ++p) {
            int r = r0 + 4 * p;
            acc2 += kijv[p] * ldsT[c * 65 + r] * ldsQ[(r >> 1) * 33 + (c >> 1)];
        }
        for (int off = 32; off; off >>= 1) acc2 += __shfl_down(acc2, off);
        if (ln == 0) red4[wv] = acc2;
    }
    __syncthreads();
    if (tid == 0)
        __hip_atomic_store(&ws[T2P_OFF + blk],
                           red4[0] + red4[1] + red4[2] + red4[3],
                           __ATOMIC_RELAXED, __HIP_MEMORY_SCOPE_AGENT);

    // ---- Diagonal blocks: t1 partial for their e-range ----
    if (I == J) {
        float v = 0.0f;
        if (tid < 32) {
            float sw = 0.0f;
            for (int b2 = 0; b2 < B; ++b2) sw += We[b2 * 32 + tid];
            int e = e0 + tid;
            float dd = kwz[(size_t)(2 * e) * ND + (2 * e)]
                     + kwz[(size_t)(2 * e + 1) * ND + (2 * e + 1)];
            v = sw * dd;
        }
        for (int off = 32; off; off >>= 1) v += __shfl_down(v, off);
        if (tid == 0)
            __hip_atomic_store(&ws[T1P_OFF + I], v,
                               __ATOMIC_RELAXED, __HIP_MEMORY_SCOPE_AGENT);
    }

    // ---- Block 0: c1 = sum_e log1p(-p_e) ----
    if (blk == 0) {
        float x0 = para[tid], x1 = para[tid + 256];
        float p0 = 1.0f / (1.0f + expf(-x0)) + 1e-20f;
        float p1 = 1.0f / (1.0f + expf(-x1)) + 1e-20f;
        float s = log1pf(-p0) + log1pf(-p1);
        for (int off = 32; off; off >>= 1) s += __shfl_down(s, off);
        if (ln == 0) red4[4 + wv] = s;
        __syncthreads();
        if (tid == 0)
            __hip_atomic_store(&ws[C1_OFF],
                               red4[4] + red4[5] + red4[6] + red4[7],
                               __ATOMIC_RELAXED, __HIP_MEMORY_SCOPE_AGENT);
    }

    // ---- Ticket: last block to arrive assembles the loss (no spinning) ----
    __syncthreads();
    if (tid == 0) {
        unsigned old = __hip_atomic_fetch_add(&wsu[TICKET_OFF], 1u,
                                              __ATOMIC_ACQ_REL,
                                              __HIP_MEMORY_SCOPE_AGENT);
        amLast = (old == POISON + 255u || old == 255u) ? 1 : 0;
    }
    __syncthreads();
    if (amLast) {
        float v = __hip_atomic_load(&ws[T2P_OFF + tid], __ATOMIC_RELAXED,
                                    __HIP_MEMORY_SCOPE_AGENT) * (0.25f / (float)B);
        if (tid < 16)
            v += __hip_atomic_load(&ws[T1P_OFF + tid], __ATOMIC_RELAXED,
                                   __HIP_MEMORY_SCOPE_AGENT) * (0.5f / (float)B);
        if (tid == 0)
            v -= __hip_atomic_load(&ws[C1_OFF], __ATOMIC_RELAXED,
                                   __HIP_MEMORY_SCOPE_AGENT);
        for (int off = 32; off; off >>= 1) v += __shfl_down(v, off);
        if (ln == 0) red4[wv] = v;
        __syncthreads();
        if (tid == 0) out[0] = red4[0] + red4[1] + red4[2] + red4[3];
    }
}

extern "C" void kernel_launch(void* const* d_in, const int* in_sizes, int n_in,
                              void* d_out, int out_size, void* d_ws, size_t ws_size,
                              hipStream_t stream) {
    const int*   det  = (const int*)d_in[0];    // [B, D]
    const int*   pebz = (const int*)d_in[1];    // [D, E]
    const float* para = (const float*)d_in[2];  // [E]
    const float* kwz  = (const float*)d_in[3];  // [ND, ND]
    // d_in[4] = edges_dict_z (arange(ND)//2, deterministic -> hardcoded)
    float* ws  = (float*)d_ws;
    float* out = (float*)d_out;

    hipLaunchKernelGGL(fused_k, dim3(256), dim3(256), 0, stream,
                       det, pebz, para, kwz, ws, out);
}

// Round 7
// 79.738 us; speedup vs baseline: 1.3592x; 1.1984x over previous
//
#include <hip/hip_runtime.h>
#include <math.h>

// Problem constants (fixed by the reference):
#define B  64
#define D  256
#define E  512
#define ND 1024

#define POISON 0xAAAAAAAAu

// ws offsets (4-byte units). Harness poisons ws with 0xAA before every launch.
#define TICKET_OFF 0      // [1]   uint ticket (starts at POISON)
#define C1_OFF     64     // [1]   float: sum_e log1p(-p_e)
#define T1P_OFF    128    // [16]  t1 partials (diagonal tiles)
#define T2P_OFF    256    // [256] t2 partials (one per tile)

// One block per 64x64 directed tile (I,J) of kwz <-> 32x32 undirected (e,f) tile.
// All global loads are issued up-front into register arrays (structural MLP,
// no ballot/lane-0 serialization); bit-packing is per-thread local. No
// inter-block sync except the final atomic ticket.
__global__ __launch_bounds__(256, 1) void fused_k(const int* __restrict__ det,
                                                  const int* __restrict__ pebz,
                                                  const float* __restrict__ para,
                                                  const float* __restrict__ kwz,
                                                  float* __restrict__ ws,
                                                  float* __restrict__ out) {
    unsigned* wsu = (unsigned*)ws;
    const int blk = blockIdx.x;   // 0..255
    const int tid = threadIdx.x;  // 0..255
    const int wv  = tid >> 6;     // wave 0..3
    const int ln  = tid & 63;     // lane 0..63
    const int I = blk >> 4, J = blk & 15;
    const int e0 = I * 32, f0 = J * 32;

    __shared__ unsigned long long detw[64 * 5];  // [b*5+seg]: bit l <-> d=seg*64+l
    __shared__ unsigned long long mask[256];     // [d]: bit c over block's 64 cols
    __shared__ unsigned long long segP[256];     // per-seg parity partials
    __shared__ unsigned long long Pb[64];        // [b] parity bits over 64 cols
    __shared__ float wcols[64];                  // w = p/(1-p) for the 64 cols
    __shared__ float We[64 * 32];                // W[b][e-tile]
    __shared__ float Wf[64 * 32];                // W[b][f-tile]
    __shared__ float ldsQ[32 * 33];              // Q tile (pad 33)
    __shared__ float ldsT[64 * 65];              // kwz^T tile (pad 65: 2-way, free)
    __shared__ float red4[8];
    __shared__ int   amLast;

    // ---- 1) kwz tile loads first (coldest; coalesced b32; kijv lives long) ----
    float kijv[16], kjiv[16];
    #pragma unroll
    for (int p = 0; p < 16; ++p)
        kijv[p] = kwz[(size_t)(I * 64 + wv + 4 * p) * ND + (J * 64 + ln)];
    #pragma unroll
    for (int p = 0; p < 16; ++p)
        kjiv[p] = kwz[(size_t)(J * 64 + wv + 4 * p) * ND + (I * 64 + ln)];

    // ---- 2) pebz: thread tid owns row d=tid; 16 int4 = the block's 64 cols ----
    const int4* pz4 = (const int4*)pebz;
    int4 pv[16];
    {
        const int rowb = tid * (E / 4);
        #pragma unroll
        for (int k = 0; k < 8; ++k) pv[k]     = pz4[rowb + (e0 >> 2) + k];
        #pragma unroll
        for (int k = 0; k < 8; ++k) pv[8 + k] = pz4[rowb + (f0 >> 2) + k];
    }

    // ---- 3) det: 4 threads per b (seg=tid&3); 16 int4 = 64 d-columns ----
    const int4* dt4 = (const int4*)det;
    int4 dv[16];
    {
        const int b = tid >> 2, seg = tid & 3;
        #pragma unroll
        for (int k = 0; k < 16; ++k) dv[k] = dt4[b * 64 + seg * 16 + k];
    }

    // ---- 4) para -> wcols (wave 1; single round, overlaps the above) ----
    if (wv == 1) {
        int col = (ln < 32) ? (e0 + ln) : (f0 + ln - 32);
        float x = para[col];
        float prob = 1.0f / (1.0f + expf(-x)) + 1e-20f;
        wcols[ln] = prob / (1.0f - prob);
    }

    // ---- 5) stage kji tile to LDS (consumes kjiv; pv/dv still in flight) ----
    #pragma unroll
    for (int p = 0; p < 16; ++p)
        ldsT[(wv + 4 * p) * 65 + ln] = kjiv[p];

    // ---- 6) pack pebz bits locally -> one LDS store (no ballot) ----
    {
        unsigned long long m = 0ULL;
        #pragma unroll
        for (int k = 0; k < 8; ++k) {
            m |= (unsigned long long)(pv[k].x != 0) << (4 * k + 0);
            m |= (unsigned long long)(pv[k].y != 0) << (4 * k + 1);
            m |= (unsigned long long)(pv[k].z != 0) << (4 * k + 2);
            m |= (unsigned long long)(pv[k].w != 0) << (4 * k + 3);
            m |= (unsigned long long)(pv[8 + k].x != 0) << (32 + 4 * k + 0);
            m |= (unsigned long long)(pv[8 + k].y != 0) << (32 + 4 * k + 1);
            m |= (unsigned long long)(pv[8 + k].z != 0) << (32 + 4 * k + 2);
            m |= (unsigned long long)(pv[8 + k].w != 0) << (32 + 4 * k + 3);
        }
        mask[tid] = m;
    }

    // ---- 7) pack det bits locally -> one LDS store ----
    {
        unsigned long long m = 0ULL;
        #pragma unroll
        for (int k = 0; k < 16; ++k) {
            m |= (unsigned long long)(dv[k].x != 0) << (4 * k + 0);
            m |= (unsigned long long)(dv[k].y != 0) << (4 * k + 1);
            m |= (unsigned long long)(dv[k].z != 0) << (4 * k + 2);
            m |= (unsigned long long)(dv[k].w != 0) << (4 * k + 3);
        }
        detw[(tid >> 2) * 5 + (tid & 3)] = m;
    }
    __syncthreads();

    // ---- Parity: P[b] = XOR_{d: det[b][d]=1} mask[d] (LDS-only) ----
    {
        const int b = ln, seg = wv;
        unsigned long long db = detw[b * 5 + seg];
        const unsigned long long* mp = &mask[seg * 64];
        unsigned long long m = 0ULL;
        #pragma unroll 8
        for (int l = 0; l < 64; ++l)        // mp[l] wave-broadcast (free)
            m ^= mp[l] & (0ULL - ((db >> l) & 1ULL));
        segP[seg * 64 + b] = m;
    }
    __syncthreads();
    if (tid < 64)
        Pb[tid] = segP[tid] ^ segP[64 + tid] ^ segP[128 + tid] ^ segP[192 + tid];
    __syncthreads();

    // ---- Signed weight tiles We/Wf ----
    #pragma unroll
    for (int k = 0; k < 16; ++k) {
        int pair = tid + 256 * k;
        int b  = pair >> 6;                  // wave-uniform -> Pb broadcast
        int cc = pair & 63;
        float val = wcols[cc];
        if ((Pb[b] >> cc) & 1ULL) val = -val;
        if (cc < 32) We[b * 32 + cc] = val;
        else         Wf[b * 32 + (cc - 32)] = val;
    }
    __syncthreads();

    // ---- Q tile: Q[e][f] = sum_b We[b][e]*Wf[b][f] ----
    {
        const int tf = tid & 31, teo = tid >> 5;
        float qa[4] = {0.f, 0.f, 0.f, 0.f};
        for (int b2 = 0; b2 < B; ++b2) {
            float wf = Wf[b2 * 32 + tf];
            #pragma unroll
            for (int r4 = 0; r4 < 4; ++r4)
                qa[r4] += We[b2 * 32 + teo + 8 * r4] * wf;
        }
        #pragma unroll
        for (int r4 = 0; r4 < 4; ++r4)
            ldsQ[(teo + 8 * r4) * 33 + tf] = qa[r4];
    }
    __syncthreads();

    // ---- Contraction: t2 partial = sum_tile K_ij (regs) * K_ji (LDS) * Q ----
    {
        float acc2 = 0.0f;
        #pragma unroll
        for (int p = 0; p < 16; ++p) {
            int r = wv + 4 * p;
            acc2 += kijv[p] * ldsT[ln * 65 + r] * ldsQ[(r >> 1) * 33 + (ln >> 1)];
        }
        for (int off = 32; off; off >>= 1) acc2 += __shfl_down(acc2, off);
        if (ln == 0) red4[wv] = acc2;
    }
    __syncthreads();
    if (tid == 0)
        __hip_atomic_store(&ws[T2P_OFF + blk],
                           red4[0] + red4[1] + red4[2] + red4[3],
                           __ATOMIC_RELAXED, __HIP_MEMORY_SCOPE_AGENT);

    // ---- Diagonal blocks: t1 partial for their e-range ----
    if (I == J) {
        float v = 0.0f;
        if (tid < 32) {
            float sw = 0.0f;
            for (int b2 = 0; b2 < B; ++b2) sw += We[b2 * 32 + tid];
            int e = e0 + tid;
            float dd = kwz[(size_t)(2 * e) * ND + (2 * e)]
                     + kwz[(size_t)(2 * e + 1) * ND + (2 * e + 1)];
            v = sw * dd;
        }
        for (int off = 32; off; off >>= 1) v += __shfl_down(v, off);
        if (tid == 0)
            __hip_atomic_store(&ws[T1P_OFF + I], v,
                               __ATOMIC_RELAXED, __HIP_MEMORY_SCOPE_AGENT);
    }

    // ---- Block 0: c1 = sum_e log1p(-p_e) ----
    if (blk == 0) {
        float x0 = para[tid], x1 = para[tid + 256];
        float p0 = 1.0f / (1.0f + expf(-x0)) + 1e-20f;
        float p1 = 1.0f / (1.0f + expf(-x1)) + 1e-20f;
        float s = log1pf(-p0) + log1pf(-p1);
        for (int off = 32; off; off >>= 1) s += __shfl_down(s, off);
        if (ln == 0) red4[4 + wv] = s;
        __syncthreads();
        if (tid == 0)
            __hip_atomic_store(&ws[C1_OFF],
                               red4[4] + red4[5] + red4[6] + red4[7],
                               __ATOMIC_RELAXED, __HIP_MEMORY_SCOPE_AGENT);
    }

    // ---- Ticket: last block to arrive assembles the loss (no spinning) ----
    __syncthreads();
    if (tid == 0) {
        unsigned old = __hip_atomic_fetch_add(&wsu[TICKET_OFF], 1u,
                                              __ATOMIC_ACQ_REL,
                                              __HIP_MEMORY_SCOPE_AGENT);
        amLast = (old == POISON + 255u || old == 255u) ? 1 : 0;
    }
    __syncthreads();
    if (amLast) {
        float v = __hip_atomic_load(&ws[T2P_OFF + tid], __ATOMIC_RELAXED,
                                    __HIP_MEMORY_SCOPE_AGENT) * (0.25f / (float)B);
        if (tid < 16)
            v += __hip_atomic_load(&ws[T1P_OFF + tid], __ATOMIC_RELAXED,
                                   __HIP_MEMORY_SCOPE_AGENT) * (0.5f / (float)B);
        if (tid == 0)
            v -= __hip_atomic_load(&ws[C1_OFF], __ATOMIC_RELAXED,
                                   __HIP_MEMORY_SCOPE_AGENT);
        for (int off = 32; off; off >>= 1) v += __shfl_down(v, off);
        if (ln == 0) red4[wv] = v;
        __syncthreads();
        if (tid == 0) out[0] = red4[0] + red4[1] + red4[2] + red4[3];
    }
}

extern "C" void kernel_launch(void* const* d_in, const int* in_sizes, int n_in,
                              void* d_out, int out_size, void* d_ws, size_t ws_size,
                              hipStream_t stream) {
    const int*   det  = (const int*)d_in[0];    // [B, D]
    const int*   pebz = (const int*)d_in[1];    // [D, E]
    const float* para = (const float*)d_in[2];  // [E]
    const float* kwz  = (const float*)d_in[3];  // [ND, ND]
    // d_in[4] = edges_dict_z (arange(ND)//2, deterministic -> hardcoded)
    float* ws  = (float*)d_ws;
    float* out = (float*)d_out;

    hipLaunchKernelGGL(fused_k, dim3(256), dim3(256), 0, stream,
                       det, pebz, para, kwz, ws, out);
}

// Round 8
// 78.858 us; speedup vs baseline: 1.3744x; 1.0112x over previous
//
#include <hip/hip_runtime.h>
#include <math.h>

// Problem constants (fixed by the reference):
#define B  64
#define D  256
#define E  512
#define ND 1024

#define POISON 0xAAAAAAAAu

// ws offsets (4-byte units). Harness poisons ws with 0xAA before every launch.
#define GLB_OFF  0        // [1]   global arrival counter (16 group-winners add)
#define C1_OFF   16       // [1]   float: sum_e log1p(-p_e)
#define T1P_OFF  32       // [16]  t1 partials (diagonal tiles)
#define T2P_OFF  64       // [256] t2 partials (one per tile)
#define GRP_OFF  512      // [16 counters, spaced 64 units = 256 B apart]

// One block per 64x64 directed tile (I,J) of kwz <-> 32x32 undirected (e,f) tile.
// All global loads are issued up-front into register arrays (structural MLP);
// bit-packing is per-thread local. Finish: relaxed device-scope hierarchical
// ticket (16 group lines + 1 global) — no ACQ_REL cache maintenance, ordering
// guaranteed by the vmcnt(0) drain inside __syncthreads before each arrival add.
__global__ __launch_bounds__(256, 1) void fused_k(const int* __restrict__ det,
                                                  const int* __restrict__ pebz,
                                                  const float* __restrict__ para,
                                                  const float* __restrict__ kwz,
                                                  float* __restrict__ ws,
                                                  float* __restrict__ out) {
    unsigned* wsu = (unsigned*)ws;
    const int blk = blockIdx.x;   // 0..255
    const int tid = threadIdx.x;  // 0..255
    const int wv  = tid >> 6;     // wave 0..3
    const int ln  = tid & 63;     // lane 0..63
    const int I = blk >> 4, J = blk & 15;
    const int e0 = I * 32, f0 = J * 32;

    __shared__ unsigned long long detw[64 * 5];  // [b*5+seg]: bit l <-> d=seg*64+l
    __shared__ unsigned long long mask[256];     // [d]: bit c over block's 64 cols
    __shared__ unsigned long long segP[256];     // per-seg parity partials
    __shared__ unsigned long long Pb[64];        // [b] parity bits over 64 cols
    __shared__ float wcols[64];                  // w = p/(1-p) for the 64 cols
    __shared__ float We[64 * 32];                // W[b][e-tile]
    __shared__ float Wf[64 * 32];                // W[b][f-tile]
    __shared__ float ldsQ[32 * 33];              // Q tile (pad 33)
    __shared__ float ldsT[64 * 65];              // kwz^T tile (pad 65: 2-way, free)
    __shared__ float red4[8];
    __shared__ int   amLast;

    // ---- 1) kwz tile loads first (coldest; coalesced b32; kijv lives long) ----
    float kijv[16], kjiv[16];
    #pragma unroll
    for (int p = 0; p < 16; ++p)
        kijv[p] = kwz[(size_t)(I * 64 + wv + 4 * p) * ND + (J * 64 + ln)];
    #pragma unroll
    for (int p = 0; p < 16; ++p)
        kjiv[p] = kwz[(size_t)(J * 64 + wv + 4 * p) * ND + (I * 64 + ln)];

    // ---- 2) pebz: thread tid owns row d=tid; 16 int4 = the block's 64 cols ----
    const int4* pz4 = (const int4*)pebz;
    int4 pv[16];
    {
        const int rowb = tid * (E / 4);
        #pragma unroll
        for (int k = 0; k < 8; ++k) pv[k]     = pz4[rowb + (e0 >> 2) + k];
        #pragma unroll
        for (int k = 0; k < 8; ++k) pv[8 + k] = pz4[rowb + (f0 >> 2) + k];
    }

    // ---- 3) det: 4 threads per b (seg=tid&3); 16 int4 = 64 d-columns ----
    const int4* dt4 = (const int4*)det;
    int4 dv[16];
    {
        const int b = tid >> 2, seg = tid & 3;
        #pragma unroll
        for (int k = 0; k < 16; ++k) dv[k] = dt4[b * 64 + seg * 16 + k];
    }

    // ---- 4) para -> wcols (wave 1; single round, overlaps the above) ----
    if (wv == 1) {
        int col = (ln < 32) ? (e0 + ln) : (f0 + ln - 32);
        float x = para[col];
        float prob = 1.0f / (1.0f + expf(-x)) + 1e-20f;
        wcols[ln] = prob / (1.0f - prob);
    }

    // ---- 5) stage kji tile to LDS (consumes kjiv; pv/dv still in flight) ----
    #pragma unroll
    for (int p = 0; p < 16; ++p)
        ldsT[(wv + 4 * p) * 65 + ln] = kjiv[p];

    // ---- 6) pack pebz bits locally -> one LDS store (no ballot) ----
    {
        unsigned long long m = 0ULL;
        #pragma unroll
        for (int k = 0; k < 8; ++k) {
            m |= (unsigned long long)(pv[k].x != 0) << (4 * k + 0);
            m |= (unsigned long long)(pv[k].y != 0) << (4 * k + 1);
            m |= (unsigned long long)(pv[k].z != 0) << (4 * k + 2);
            m |= (unsigned long long)(pv[k].w != 0) << (4 * k + 3);
            m |= (unsigned long long)(pv[8 + k].x != 0) << (32 + 4 * k + 0);
            m |= (unsigned long long)(pv[8 + k].y != 0) << (32 + 4 * k + 1);
            m |= (unsigned long long)(pv[8 + k].z != 0) << (32 + 4 * k + 2);
            m |= (unsigned long long)(pv[8 + k].w != 0) << (32 + 4 * k + 3);
        }
        mask[tid] = m;
    }

    // ---- 7) pack det bits locally -> one LDS store ----
    {
        unsigned long long m = 0ULL;
        #pragma unroll
        for (int k = 0; k < 16; ++k) {
            m |= (unsigned long long)(dv[k].x != 0) << (4 * k + 0);
            m |= (unsigned long long)(dv[k].y != 0) << (4 * k + 1);
            m |= (unsigned long long)(dv[k].z != 0) << (4 * k + 2);
            m |= (unsigned long long)(dv[k].w != 0) << (4 * k + 3);
        }
        detw[(tid >> 2) * 5 + (tid & 3)] = m;
    }
    __syncthreads();

    // ---- Parity: P[b] = XOR_{d: det[b][d]=1} mask[d] (LDS-only) ----
    {
        const int b = ln, seg = wv;
        unsigned long long db = detw[b * 5 + seg];
        const unsigned long long* mp = &mask[seg * 64];
        unsigned long long m = 0ULL;
        #pragma unroll 8
        for (int l = 0; l < 64; ++l)        // mp[l] wave-broadcast (free)
            m ^= mp[l] & (0ULL - ((db >> l) & 1ULL));
        segP[seg * 64 + b] = m;
    }
    __syncthreads();
    if (tid < 64)
        Pb[tid] = segP[tid] ^ segP[64 + tid] ^ segP[128 + tid] ^ segP[192 + tid];
    __syncthreads();

    // ---- Signed weight tiles We/Wf ----
    #pragma unroll
    for (int k = 0; k < 16; ++k) {
        int pair = tid + 256 * k;
        int b  = pair >> 6;                  // wave-uniform -> Pb broadcast
        int cc = pair & 63;
        float val = wcols[cc];
        if ((Pb[b] >> cc) & 1ULL) val = -val;
        if (cc < 32) We[b * 32 + cc] = val;
        else         Wf[b * 32 + (cc - 32)] = val;
    }
    __syncthreads();

    // ---- Q tile: Q[e][f] = sum_b We[b][e]*Wf[b][f] ----
    {
        const int tf = tid & 31, teo = tid >> 5;
        float qa[4] = {0.f, 0.f, 0.f, 0.f};
        for (int b2 = 0; b2 < B; ++b2) {
            float wf = Wf[b2 * 32 + tf];
            #pragma unroll
            for (int r4 = 0; r4 < 4; ++r4)
                qa[r4] += We[b2 * 32 + teo + 8 * r4] * wf;
        }
        #pragma unroll
        for (int r4 = 0; r4 < 4; ++r4)
            ldsQ[(teo + 8 * r4) * 33 + tf] = qa[r4];
    }
    __syncthreads();

    // ---- Contraction: t2 partial = sum_tile K_ij (regs) * K_ji (LDS) * Q ----
    {
        float acc2 = 0.0f;
        #pragma unroll
        for (int p = 0; p < 16; ++p) {
            int r = wv + 4 * p;
            acc2 += kijv[p] * ldsT[ln * 65 + r] * ldsQ[(r >> 1) * 33 + (ln >> 1)];
        }
        for (int off = 32; off; off >>= 1) acc2 += __shfl_down(acc2, off);
        if (ln == 0) red4[wv] = acc2;
    }
    __syncthreads();
    if (tid == 0)
        __hip_atomic_store(&ws[T2P_OFF + blk],
                           red4[0] + red4[1] + red4[2] + red4[3],
                           __ATOMIC_RELAXED, __HIP_MEMORY_SCOPE_AGENT);

    // ---- Diagonal blocks: t1 partial for their e-range ----
    if (I == J) {
        float v = 0.0f;
        if (tid < 32) {
            float sw = 0.0f;
            for (int b2 = 0; b2 < B; ++b2) sw += We[b2 * 32 + tid];
            int e = e0 + tid;
            float dd = kwz[(size_t)(2 * e) * ND + (2 * e)]
                     + kwz[(size_t)(2 * e + 1) * ND + (2 * e + 1)];
            v = sw * dd;
        }
        for (int off = 32; off; off >>= 1) v += __shfl_down(v, off);
        if (tid == 0)
            __hip_atomic_store(&ws[T1P_OFF + I], v,
                               __ATOMIC_RELAXED, __HIP_MEMORY_SCOPE_AGENT);
    }

    // ---- Block 0: c1 = sum_e log1p(-p_e) ----
    if (blk == 0) {
        float x0 = para[tid], x1 = para[tid + 256];
        float p0 = 1.0f / (1.0f + expf(-x0)) + 1e-20f;
        float p1 = 1.0f / (1.0f + expf(-x1)) + 1e-20f;
        float s = log1pf(-p0) + log1pf(-p1);
        for (int off = 32; off; off >>= 1) s += __shfl_down(s, off);
        if (ln == 0) red4[4 + wv] = s;
        __syncthreads();
        if (tid == 0)
            __hip_atomic_store(&ws[C1_OFF],
                               red4[4] + red4[5] + red4[6] + red4[7],
                               __ATOMIC_RELAXED, __HIP_MEMORY_SCOPE_AGENT);
    }

    // ---- Hierarchical relaxed arrival (no spins, no cache maintenance) ----
    // __syncthreads drains vmcnt(0): this block's relaxed agent-scope partial
    // stores are at the coherence point before the ticket add issues.
    __syncthreads();
    if (tid == 0) {
        unsigned oldg = __hip_atomic_fetch_add(&wsu[GRP_OFF + (blk >> 4) * 64], 1u,
                                               __ATOMIC_RELAXED,
                                               __HIP_MEMORY_SCOPE_AGENT);
        int grpLast = (oldg == POISON + 15u || oldg == 15u);
        unsigned olda = 0u;
        if (grpLast)
            olda = __hip_atomic_fetch_add(&wsu[GLB_OFF], 1u,
                                          __ATOMIC_RELAXED,
                                          __HIP_MEMORY_SCOPE_AGENT);
        amLast = (grpLast && (olda == POISON + 15u || olda == 15u)) ? 1 : 0;
    }
    __syncthreads();
    if (amLast) {
        float v = __hip_atomic_load(&ws[T2P_OFF + tid], __ATOMIC_RELAXED,
                                    __HIP_MEMORY_SCOPE_AGENT) * (0.25f / (float)B);
        if (tid < 16)
            v += __hip_atomic_load(&ws[T1P_OFF + tid], __ATOMIC_RELAXED,
                                   __HIP_MEMORY_SCOPE_AGENT) * (0.5f / (float)B);
        if (tid == 0)
            v -= __hip_atomic_load(&ws[C1_OFF], __ATOMIC_RELAXED,
                                   __HIP_MEMORY_SCOPE_AGENT);
        for (int off = 32; off; off >>= 1) v += __shfl_down(v, off);
        if (ln == 0) red4[wv] = v;
        __syncthreads();
        if (tid == 0) out[0] = red4[0] + red4[1] + red4[2] + red4[3];
    }
}

extern "C" void kernel_launch(void* const* d_in, const int* in_sizes, int n_in,
                              void* d_out, int out_size, void* d_ws, size_t ws_size,
                              hipStream_t stream) {
    const int*   det  = (const int*)d_in[0];    // [B, D]
    const int*   pebz = (const int*)d_in[1];    // [D, E]
    const float* para = (const float*)d_in[2];  // [E]
    const float* kwz  = (const float*)d_in[3];  // [ND, ND]
    // d_in[4] = edges_dict_z (arange(ND)//2, deterministic -> hardcoded)
    float* ws  = (float*)d_ws;
    float* out = (float*)d_out;

    hipLaunchKernelGGL(fused_k, dim3(256), dim3(256), 0, stream,
                       det, pebz, para, kwz, ws, out);
}

// Round 9
// 75.216 us; speedup vs baseline: 1.4409x; 1.0484x over previous
//
#include <hip/hip_runtime.h>
#include <math.h>

// Problem constants (fixed by the reference):
#define B  64
#define D  256
#define E  512
#define ND 1024

#define POISON 0xAAAAAAAAu

// ws offsets (4-byte units). Harness poisons ws with 0xAA before every launch.
#define GLB_OFF   0       // [1]   global arrival counter (16 group-winners add)
#define C1_OFF    16      // [1]   float: sum_e log1p(-p_e)   (written by pack_k)
#define T1P_OFF   32      // [16]  t1 partials (diagonal tiles)
#define T2P_OFF   64      // [256] t2 partials (one per tile)
#define GRP_OFF   512     // [16 counters, spaced 64 units = 256 B apart]
#define WCOL_OFF  2048    // [512] float w_e = p/(1-p)        (written by pack_k)
#define DMK_OFF   2560    // u64[64*4]: det bits, [b*4+s] bit l <-> d = s*64+l
#define PMT_OFF   3072    // u64[8*256]: pebz bits TRANSPOSED, [g*256+d] bit c <-> col g*64+c

// ---------------- Kernel A: one-time coalesced packing ----------------
// blocks 0..15: pebz rows [blk*16,+16) -> pmaskT   (LDS bounce, coalesced)
// blocks 16,17: det rows b in [0,32)/[32,64) -> dmask
// block  18   : para -> w[e] + c1
__global__ __launch_bounds__(256) void pack_k(const int* __restrict__ det,
                                              const int* __restrict__ pebz,
                                              const float* __restrict__ para,
                                              float* __restrict__ ws) {
    unsigned long long* dmk = (unsigned long long*)(ws + DMK_OFF);
    unsigned long long* pmt = (unsigned long long*)(ws + PMT_OFF);
    const int blk = blockIdx.x, tid = threadIdx.x;

    __shared__ int4  lds[2080];      // 33.3 KB bounce buffer (row stride padded)
    __shared__ float redA[8];

    if (blk < 16) {
        // ---- pebz chunk: 16 rows x 512 ints = 2048 int4, coalesced -> LDS ----
        const int4* pz4 = (const int4*)pebz;
        #pragma unroll
        for (int k = 0; k < 8; ++k) {
            int idx = tid + 256 * k;          // 0..2047
            int r = idx >> 7, c4 = idx & 127; // row-local, int4-col
            lds[r * 129 + c4] = pz4[(blk * 16 + r) * 128 + c4];
        }
        __syncthreads();
        // ---- pack: thread owns (d_loc, g); 16 int4 from LDS -> one u64 ----
        if (tid < 128) {
            int dloc = tid >> 3, g = tid & 7;
            unsigned long long m = 0ULL;
            #pragma unroll
            for (int k = 0; k < 16; ++k) {
                int4 v = lds[dloc * 129 + g * 16 + k];
                m |= (unsigned long long)(v.x != 0) << (4 * k + 0);
                m |= (unsigned long long)(v.y != 0) << (4 * k + 1);
                m |= (unsigned long long)(v.z != 0) << (4 * k + 2);
                m |= (unsigned long long)(v.w != 0) << (4 * k + 3);
            }
            pmt[g * 256 + blk * 16 + dloc] = m;   // transposed: consumers read contiguous d
        }
    } else if (blk < 18) {
        // ---- det chunk: 32 b-rows x 256 ints = 2048 int4 -> LDS ----
        const int b0 = (blk - 16) * 32;
        const int4* dt4 = (const int4*)det;
        #pragma unroll
        for (int k = 0; k < 8; ++k) {
            int idx = tid + 256 * k;          // 0..2047
            int r = idx >> 6, c4 = idx & 63;  // b-local row, int4-col
            lds[r * 65 + c4] = dt4[(b0 + r) * 64 + c4];
        }
        __syncthreads();
        if (tid < 128) {
            int bloc = tid >> 2, s = tid & 3;
            unsigned long long m = 0ULL;
            #pragma unroll
            for (int k = 0; k < 16; ++k) {
                int4 v = lds[bloc * 65 + s * 16 + k];
                m |= (unsigned long long)(v.x != 0) << (4 * k + 0);
                m |= (unsigned long long)(v.y != 0) << (4 * k + 1);
                m |= (unsigned long long)(v.z != 0) << (4 * k + 2);
                m |= (unsigned long long)(v.w != 0) << (4 * k + 3);
            }
            dmk[(b0 + bloc) * 4 + s] = m;
        }
    } else {
        // ---- para -> w[e]; c1 = sum_e log1p(-p_e) ----
        float x0 = para[tid], x1 = para[tid + 256];
        float p0 = 1.0f / (1.0f + expf(-x0)) + 1e-20f;
        float p1 = 1.0f / (1.0f + expf(-x1)) + 1e-20f;
        ws[WCOL_OFF + tid]       = p0 / (1.0f - p0);
        ws[WCOL_OFF + tid + 256] = p1 / (1.0f - p1);
        float s = log1pf(-p0) + log1pf(-p1);
        for (int off = 32; off; off >>= 1) s += __shfl_down(s, off);
        if ((tid & 63) == 0) redA[tid >> 6] = s;
        __syncthreads();
        if (tid == 0) ws[C1_OFF] = redA[0] + redA[1] + redA[2] + redA[3];
    }
}

// ---------------- Kernel B: per-tile compute (all loads coalesced) ----------------
// One block per 64x64 directed tile (I,J) of kwz <-> 32x32 undirected (e,f) tile.
__global__ __launch_bounds__(256) void fused_k(const float* __restrict__ kwz,
                                               float* __restrict__ ws,
                                               float* __restrict__ out) {
    unsigned* wsu = (unsigned*)ws;
    const unsigned long long* dmk = (const unsigned long long*)(ws + DMK_OFF);
    const unsigned long long* pmt = (const unsigned long long*)(ws + PMT_OFF);
    const int blk = blockIdx.x;   // 0..255
    const int tid = threadIdx.x;  // 0..255
    const int wv  = tid >> 6;     // wave 0..3
    const int ln  = tid & 63;     // lane 0..63
    const int I = blk >> 4, J = blk & 15;
    const int e0 = I * 32, f0 = J * 32;

    __shared__ unsigned long long detw[64 * 5];  // [b*5+s]: bit l <-> d = s*64+l
    __shared__ unsigned long long mask[256];     // [d]: bit c over block's 64 cols
    __shared__ unsigned long long segP[256];     // per-seg parity partials
    __shared__ unsigned long long Pb[64];        // [b] parity bits over 64 cols
    __shared__ float wcols[64];                  // w for the 64 cols
    __shared__ float We[64 * 32];                // W[b][e-tile]
    __shared__ float Wf[64 * 32];                // W[b][f-tile]
    __shared__ float ldsQ[32 * 33];              // Q tile (pad 33)
    __shared__ float ldsT[64 * 65];              // kwz^T tile (pad 65: 2-way, free)
    __shared__ float red4[8];
    __shared__ int   amLast;

    // ---- All global loads up-front, all coalesced ----
    float kijv[16], kjiv[16];
    #pragma unroll
    for (int p = 0; p < 16; ++p)
        kijv[p] = kwz[(size_t)(I * 64 + wv + 4 * p) * ND + (J * 64 + ln)];
    #pragma unroll
    for (int p = 0; p < 16; ++p)
        kjiv[p] = kwz[(size_t)(J * 64 + wv + 4 * p) * ND + (I * 64 + ln)];

    unsigned long long pa = pmt[(I >> 1) * 256 + tid];  // row d=tid, e-group bits
    unsigned long long pb = pmt[(J >> 1) * 256 + tid];  // row d=tid, f-group bits
    unsigned long long dm = dmk[tid];                   // det bits, (b,s)=(tid>>2,tid&3)
    if (wv == 1) {
        int col = (ln < 32) ? (e0 + ln) : (f0 + ln - 32);
        wcols[ln] = ws[WCOL_OFF + col];
    }

    // ---- Stage to LDS ----
    #pragma unroll
    for (int p = 0; p < 16; ++p)
        ldsT[(wv + 4 * p) * 65 + ln] = kjiv[p];
    {
        unsigned aHalf = (I & 1) ? (unsigned)(pa >> 32) : (unsigned)pa;
        unsigned bHalf = (J & 1) ? (unsigned)(pb >> 32) : (unsigned)pb;
        mask[tid] = (unsigned long long)aHalf | ((unsigned long long)bHalf << 32);
    }
    detw[(tid >> 2) * 5 + (tid & 3)] = dm;
    __syncthreads();

    // ---- Parity: P[b] = XOR_{d: det[b][d]=1} mask[d] (LDS-only) ----
    {
        const int b = ln, seg = wv;
        unsigned long long db = detw[b * 5 + seg];
        const unsigned long long* mp = &mask[seg * 64];
        unsigned long long m = 0ULL;
        #pragma unroll 8
        for (int l = 0; l < 64; ++l)        // mp[l] wave-broadcast (free)
            m ^= mp[l] & (0ULL - ((db >> l) & 1ULL));
        segP[seg * 64 + b] = m;
    }
    __syncthreads();
    if (tid < 64)
        Pb[tid] = segP[tid] ^ segP[64 + tid] ^ segP[128 + tid] ^ segP[192 + tid];
    __syncthreads();

    // ---- Signed weight tiles We/Wf ----
    #pragma unroll
    for (int k = 0; k < 16; ++k) {
        int pair = tid + 256 * k;
        int b  = pair >> 6;                  // wave-uniform -> Pb broadcast
        int cc = pair & 63;
        float val = wcols[cc];
        if ((Pb[b] >> cc) & 1ULL) val = -val;
        if (cc < 32) We[b * 32 + cc] = val;
        else         Wf[b * 32 + (cc - 32)] = val;
    }
    __syncthreads();

    // ---- Q tile: Q[e][f] = sum_b We[b][e]*Wf[b][f] ----
    {
        const int tf = tid & 31, teo = tid >> 5;
        float qa[4] = {0.f, 0.f, 0.f, 0.f};
        for (int b2 = 0; b2 < B; ++b2) {
            float wf = Wf[b2 * 32 + tf];
            #pragma unroll
            for (int r4 = 0; r4 < 4; ++r4)
                qa[r4] += We[b2 * 32 + teo + 8 * r4] * wf;
        }
        #pragma unroll
        for (int r4 = 0; r4 < 4; ++r4)
            ldsQ[(teo + 8 * r4) * 33 + tf] = qa[r4];
    }
    __syncthreads();

    // ---- Contraction: t2 partial = sum_tile K_ij (regs) * K_ji (LDS) * Q ----
    {
        float acc2 = 0.0f;
        #pragma unroll
        for (int p = 0; p < 16; ++p) {
            int r = wv + 4 * p;
            acc2 += kijv[p] * ldsT[ln * 65 + r] * ldsQ[(r >> 1) * 33 + (ln >> 1)];
        }
        for (int off = 32; off; off >>= 1) acc2 += __shfl_down(acc2, off);
        if (ln == 0) red4[wv] = acc2;
    }
    __syncthreads();
    if (tid == 0)
        __hip_atomic_store(&ws[T2P_OFF + blk],
                           red4[0] + red4[1] + red4[2] + red4[3],
                           __ATOMIC_RELAXED, __HIP_MEMORY_SCOPE_AGENT);

    // ---- Diagonal blocks: t1 partial for their e-range ----
    if (I == J) {
        float v = 0.0f;
        if (tid < 32) {
            float sw = 0.0f;
            for (int b2 = 0; b2 < B; ++b2) sw += We[b2 * 32 + tid];
            int e = e0 + tid;
            float dd = kwz[(size_t)(2 * e) * ND + (2 * e)]
                     + kwz[(size_t)(2 * e + 1) * ND + (2 * e + 1)];
            v = sw * dd;
        }
        for (int off = 32; off; off >>= 1) v += __shfl_down(v, off);
        if (tid == 0)
            __hip_atomic_store(&ws[T1P_OFF + I], v,
                               __ATOMIC_RELAXED, __HIP_MEMORY_SCOPE_AGENT);
    }

    // ---- Hierarchical relaxed arrival (no spins, no cache maintenance) ----
    __syncthreads();   // drains vmcnt(0): partial stores at coherence point first
    if (tid == 0) {
        unsigned oldg = __hip_atomic_fetch_add(&wsu[GRP_OFF + (blk >> 4) * 64], 1u,
                                               __ATOMIC_RELAXED,
                                               __HIP_MEMORY_SCOPE_AGENT);
        int grpLast = (oldg == POISON + 15u || oldg == 15u);
        unsigned olda = 0u;
        if (grpLast)
            olda = __hip_atomic_fetch_add(&wsu[GLB_OFF], 1u,
                                          __ATOMIC_RELAXED,
                                          __HIP_MEMORY_SCOPE_AGENT);
        amLast = (grpLast && (olda == POISON + 15u || olda == 15u)) ? 1 : 0;
    }
    __syncthreads();
    if (amLast) {
        float v = __hip_atomic_load(&ws[T2P_OFF + tid], __ATOMIC_RELAXED,
                                    __HIP_MEMORY_SCOPE_AGENT) * (0.25f / (float)B);
        if (tid < 16)
            v += __hip_atomic_load(&ws[T1P_OFF + tid], __ATOMIC_RELAXED,
                                   __HIP_MEMORY_SCOPE_AGENT) * (0.5f / (float)B);
        if (tid == 0)
            v -= __hip_atomic_load(&ws[C1_OFF], __ATOMIC_RELAXED,
                                   __HIP_MEMORY_SCOPE_AGENT);
        for (int off = 32; off; off >>= 1) v += __shfl_down(v, off);
        if (ln == 0) red4[wv] = v;
        __syncthreads();
        if (tid == 0) out[0] = red4[0] + red4[1] + red4[2] + red4[3];
    }
}

extern "C" void kernel_launch(void* const* d_in, const int* in_sizes, int n_in,
                              void* d_out, int out_size, void* d_ws, size_t ws_size,
                              hipStream_t stream) {
    const int*   det  = (const int*)d_in[0];    // [B, D]
    const int*   pebz = (const int*)d_in[1];    // [D, E]
    const float* para = (const float*)d_in[2];  // [E]
    const float* kwz  = (const float*)d_in[3];  // [ND, ND]
    // d_in[4] = edges_dict_z (arange(ND)//2, deterministic -> hardcoded)
    float* ws  = (float*)d_ws;
    float* out = (float*)d_out;

    hipLaunchKernelGGL(pack_k, dim3(19), dim3(256), 0, stream,
                       det, pebz, para, ws);
    hipLaunchKernelGGL(fused_k, dim3(256), dim3(256), 0, stream,
                       kwz, ws, out);
}